// Round 7
// baseline (131.576 us; speedup 1.0000x reference)
//
#include <hip/hip_runtime.h>
#include <hip/hip_bf16.h>
#include <stdint.h>

#define P    300
#define HID  128
#define NG   1000
#define ARC  75          // nodes per arc-block (4 arcs per ring)
#define NTT  5           // 16-row tiles per arc (80 rows: 79 h1 + 1 pad)

typedef __attribute__((ext_vector_type(8))) short bf16x8;
typedef __attribute__((ext_vector_type(4))) float f32x4;

// Swizzled bf16 W^T. Slot fkey holds weights for column perm(fkey):
// W2 (pass1): perm(fkey) = u*32 + 2*(fkey&15) + ((fkey>>4)&1), u=fkey>>5.
// W3 (pass2): natural. chunk(fkey,kc) at slot fkey*16 + (kc ^ (fkey&15)).
__device__ short g_wsw[2 * HID * HID];
__device__ float g_pool[NG * HID];       // per-graph column sums of relu(h3)

__device__ __forceinline__ short f2bf(float f) {
    union { float f; uint32_t u; } v; v.f = f;
    uint32_t r = v.u + 0x7fffu + ((v.u >> 16) & 1u);   // RNE
    return (short)(r >> 16);
}
__device__ __forceinline__ float bf2f(short s) {
    union { uint32_t u; float f; } v; v.u = ((uint32_t)(uint16_t)s) << 16;
    return v.f;
}
__device__ __forceinline__ uint32_t pkbf2(float a, float b) {   // low=a, high=b
    union { __hip_bfloat162 h; uint32_t u; } cv;
    cv.h = __float22bfloat162_rn(float2{a, b});
    return cv.u;
}
__device__ __forceinline__ float unpk(int v, int ft) {
    return bf2f((short)(ft ? (((uint32_t)v) >> 16) : (v & 0xffff)));
}

__global__ __launch_bounds__(256) void k_prep(const float* __restrict__ W2,
                                              const float* __restrict__ W3) {
    int b = blockIdx.x;                       // 16 blocks
    // zero the pool accumulator (128000 floats over 4096 threads)
    int tz = b * 256 + threadIdx.x;
    #pragma unroll
    for (int i = 0; i < 32; ++i) {
        int idx = i * 4096 + tz;
        if (idx < NG * HID) g_pool[idx] = 0.f;
    }
    const bool perm = (b < 8);
    const float* W = perm ? W2 : W3;
    short* dst = g_wsw + (perm ? 0 : HID * HID);
    int t    = (b & 7) * 256 + threadIdx.x;   // 0..2047 chunks
    int fkey = t >> 4;
    int kc   = t & 15;
    int fsrc;
    if (perm) {
        int u = fkey >> 5, ft = (fkey >> 4) & 1, l = fkey & 15;
        fsrc = u * 32 + 2 * l + ft;
    } else fsrc = fkey;
    bf16x8 o;
    #pragma unroll
    for (int j = 0; j < 8; ++j)
        o[j] = f2bf(W[(kc * 8 + j) * HID + fsrc]);
    *(bf16x8*)&dst[(fkey * 16 + (kc ^ (fkey & 15))) * 8] = o;
}

__device__ __forceinline__ void avg_epi(const float* G, float vp0, float vn3,
                                        float b, float* o) {
    o[0] = (vp0  + G[0] + G[1]) * (1.0f / 3.0f) + b;
    o[1] = (G[0] + G[1] + G[2]) * (1.0f / 3.0f) + b;
    o[2] = (G[1] + G[2] + G[3]) * (1.0f / 3.0f) + b;
    o[3] = (G[2] + G[3] + vn3 ) * (1.0f / 3.0f) + b;
    #pragma unroll
    for (int i = 0; i < 4; ++i) o[i] = o[i] > 0.f ? o[i] : 0.f;
}

// One layer over an arc. G(t) = h·W on RAW h (avg3 commutes with the linear
// map); averaging on fp32 C-rows. All NTT tiles computed up front (registers),
// one barrier, then epilogues. POOL=0: store h2 rows 1..77 in place (permuted
// features, paired b32 stores). POOL=1: psum over rows 2..76 -> g_pool atomics.
template<int POOL>
__device__ __forceinline__ void run_pass(short* __restrict__ buf,
                                         const short* __restrict__ wbase,
                                         const float* __restrict__ bias,
                                         int gidx, int tid) {
    const int lane = tid & 63, wv = tid >> 6, q = lane >> 4, lm = lane & 15;
    const int ftg0 = wv * 2;
    bf16x8 wf[2][4];
    #pragma unroll
    for (int ft = 0; ft < 2; ++ft) {
        int fkey = (ftg0 + ft) * 16 + lm;
        #pragma unroll
        for (int kk = 0; kk < 4; ++kk)
            wf[ft][kk] = *(const bf16x8*)&wbase[(fkey * 16 + ((4 * kk + q) ^ lm)) * 8];
    }
    float biaf[2];
    #pragma unroll
    for (int ft = 0; ft < 2; ++ft)
        biaf[ft] = POOL ? bias[(ftg0 + ft) * 16 + lm] : bias[wv * 32 + 2 * lm + ft];
    const int sA = (q == 0) ? (48 + lm) : (lane - 16);
    const int sB = (lane + 16) & 63;
    const int fpair = wv * 32 + 2 * lm;       // even physical feature (pass1)
    const int kcs = fpair >> 3, offs = fpair & 7;

    // ---- all tiles' G up front ----
    f32x4 G[NTT][2];
    #pragma unroll
    for (int t = 0; t < NTT; ++t) {
        G[t][0] = f32x4{0.f, 0.f, 0.f, 0.f};
        G[t][1] = f32x4{0.f, 0.f, 0.f, 0.f};
        const short* tb = buf + t * 2048;
        #pragma unroll
        for (int kk = 0; kk < 4; ++kk) {
            bf16x8 af = *(const bf16x8*)&tb[(lm * 16 + ((4 * kk + q) ^ lm)) * 8];
            G[t][0] = __builtin_amdgcn_mfma_f32_16x16x32_bf16(af, wf[0][kk], G[t][0], 0, 0, 0);
            G[t][1] = __builtin_amdgcn_mfma_f32_16x16x32_bf16(af, wf[1][kk], G[t][1], 0, 0, 0);
        }
    }
    if (!POOL) __syncthreads();           // all h reads done before overwrite

    float c15[2] = {0.f, 0.f};
    float psum[2] = {0.f, 0.f};
    #pragma unroll
    for (int t = 0; t < NTT; ++t) {
        const int tn = (t < NTT - 1) ? t + 1 : t;   // last tile's vn masked anyway
        uint32_t uA = pkbf2(G[t][0][3],  G[t][1][3]);
        uint32_t uB = pkbf2(G[t][0][0],  G[t][1][0]);
        uint32_t uC = pkbf2(G[tn][0][0], G[tn][1][0]);
        int vA = __shfl((int)uA, sA, 64);
        int vB = __shfl((int)uB, sB, 64);
        int vC = __shfl((int)uC, lm, 64);
        float o2[2][4];
        #pragma unroll
        for (int ft = 0; ft < 2; ++ft) {
            float bpA = unpk(vA, ft), bpB = unpk(vB, ft), bpC = unpk(vC, ft);
            float vp0 = (q == 0) ? c15[ft] : bpA;
            float vn3 = (q == 3) ? bpC : bpB;
            avg_epi((const float*)&G[t][ft], vp0, vn3, biaf[ft], o2[ft]);
            c15[ft] = bpA;                // q0: row15 of tile t, for next iter
            if (POOL) {
                #pragma unroll
                for (int i = 0; i < 4; ++i) {
                    int r = t * 16 + q * 4 + i;
                    if (r >= 2 && r <= 76) psum[ft] += o2[ft][i];
                }
            }
        }
        if (!POOL) {
            #pragma unroll
            for (int i = 0; i < 4; ++i) {
                int r = t * 16 + q * 4 + i;
                if (r >= 1 && r <= 77)
                    *(uint32_t*)&buf[(r * 16 + (kcs ^ (r & 15))) * 8 + offs] =
                        pkbf2(o2[0][i], o2[1][i]);
            }
        }
    }

    if (POOL) {
        #pragma unroll
        for (int ft = 0; ft < 2; ++ft) {
            psum[ft] += __shfl_xor(psum[ft], 16, 64);
            psum[ft] += __shfl_xor(psum[ft], 32, 64);
        }
        if (q == 0) {
            atomicAdd(&g_pool[gidx * HID + ftg0 * 16 + lm],      psum[0]);
            atomicAdd(&g_pool[gidx * HID + ftg0 * 16 + 16 + lm], psum[1]);
        }
    }
}

// One block (256 thr) per 75-node arc; 4 arcs per ring. LDS ~21.5 KB.
__global__ __launch_bounds__(256, 4) void k_graph(
        const float* __restrict__ x,
        const float* __restrict__ W1,  const float* __restrict__ b1,
        const float* __restrict__ b2v, const float* __restrict__ b3v) {
    __shared__ __align__(16) short buf[NTT * 16 * HID];  // 80 rows, 20480 B
    __shared__ __align__(16) float xs[164];              // 81 x-pairs + pad

    const int g   = blockIdx.x >> 2;
    const int s   = (blockIdx.x & 3) * ARC;   // arc start node
    const int tid = threadIdx.x;

    // ---- stage x nodes s-3 .. s+77 (mod 300) ----
    if (tid < 81) {
        int node = s - 3 + tid;
        node += (node < 0) ? P : 0;
        node -= (node >= P) ? P : 0;
        *(float2*)&xs[2 * tid] = *(const float2*)&x[g * 600 + node * 2];
    }
    __syncthreads();

    // ---- layer 1: buf rows 0..78 <- relu(avg3(x) @ W1 + b1); row 79 zero ----
    {
        const int kc1 = tid & 15;
        const int n0  = tid >> 4;
        float w1x[8], w1y[8], b1v[8];
        #pragma unroll
        for (int j = 0; j < 8; ++j) {
            w1x[j] = W1[kc1 * 8 + j];
            w1y[j] = W1[HID + kc1 * 8 + j];
            b1v[j] = b1[kc1 * 8 + j];
        }
        #pragma unroll
        for (int it = 0; it < NTT; ++it) {
            int r = it * 16 + n0;
            uint32_t w[4] = {0u, 0u, 0u, 0u};
            if (r < 79) {
                float2 xp = *(const float2*)&xs[2 * r];
                float2 xc = *(const float2*)&xs[2 * r + 2];
                float2 xn = *(const float2*)&xs[2 * r + 4];
                float ax = (xp.x + xc.x + xn.x) * (1.f / 3.f);
                float ay = (xp.y + xc.y + xn.y) * (1.f / 3.f);
                #pragma unroll
                for (int jj = 0; jj < 4; ++jj) {
                    float va = ax * w1x[2*jj]   + ay * w1y[2*jj]   + b1v[2*jj];
                    float vb = ax * w1x[2*jj+1] + ay * w1y[2*jj+1] + b1v[2*jj+1];
                    va = va > 0.f ? va : 0.f;
                    vb = vb > 0.f ? vb : 0.f;
                    w[jj] = pkbf2(va, vb);
                }
            }
            *(uint4*)&buf[(r * 16 + (kc1 ^ (r & 15))) * 8] =
                uint4{w[0], w[1], w[2], w[3]};
        }
    }
    __syncthreads();

    run_pass<0>(buf, g_wsw,             b2v, g, tid);   // h1 -> h2 (rows 1..77)
    __syncthreads();
    run_pass<1>(buf, g_wsw + HID * HID, b3v, g, tid);   // h2 -> pooled sums
}

// FC head: pooled sums -> out. 1000 blocks x 128 threads.
__global__ __launch_bounds__(128) void k_fc(const float* __restrict__ fw1,
                                            const float* __restrict__ fb1,
                                            const float* __restrict__ fw2,
                                            const float* __restrict__ fb2,
                                            float* __restrict__ out) {
    int g = blockIdx.x, f = threadIdx.x;
    __shared__ float pl[128];
    __shared__ float s1[128];
    pl[f] = g_pool[g * HID + f] * (1.0f / 300.0f);
    __syncthreads();
    float o1 = fb1[f];
    #pragma unroll 8
    for (int k = 0; k < 128; ++k) o1 += pl[k] * fw1[k * 128 + f];
    s1[f] = o1 > 0.f ? o1 : 0.f;
    __syncthreads();
    {
        int o = f >> 6, ln = f & 63;
        float v = s1[ln] * fw2[ln * 2 + o] + s1[ln + 64] * fw2[(ln + 64) * 2 + o];
        #pragma unroll
        for (int off = 1; off <= 32; off <<= 1)
            v += __shfl_xor(v, off, 64);
        if (ln == 0) out[g * 2 + o] = v + fb2[o];
    }
}

extern "C" void kernel_launch(void* const* d_in, const int* in_sizes, int n_in,
                              void* d_out, int out_size, void* d_ws, size_t ws_size,
                              hipStream_t stream) {
    const float* x   = (const float*)d_in[0];
    const float* W1  = (const float*)d_in[3];
    const float* b1  = (const float*)d_in[4];
    const float* W2  = (const float*)d_in[5];
    const float* b2  = (const float*)d_in[6];
    const float* W3  = (const float*)d_in[7];
    const float* b3  = (const float*)d_in[8];
    const float* fw1 = (const float*)d_in[9];
    const float* fb1 = (const float*)d_in[10];
    const float* fw2 = (const float*)d_in[11];
    const float* fb2 = (const float*)d_in[12];
    float* out = (float*)d_out;

    k_prep <<<dim3(16),     dim3(256), 0, stream>>>(W2, W3);
    k_graph<<<dim3(NG * 4), dim3(256), 0, stream>>>(x, W1, b1, b2, b3);
    k_fc   <<<dim3(NG),     dim3(128), 0, stream>>>(fw1, fb1, fw2, fb2, out);
}